// Round 1
// baseline (633.851 us; speedup 1.0000x reference)
//
#include <hip/hip_runtime.h>
#include <hip/hip_bf16.h>
#include <type_traits>

#define DEVINL __device__ __forceinline__

typedef float f32x4 __attribute__((ext_vector_type(4)));
typedef __bf16 bf16x8 __attribute__((ext_vector_type(8)));

DEVINL float bf2f(short s) {
  unsigned u = ((unsigned)(unsigned short)s) << 16;
  float f; __builtin_memcpy(&f, &u, 4); return f;
}
DEVINL short f2bf(float f) {
  unsigned u; __builtin_memcpy(&u, &f, 4);
  u += 0x7fff + ((u >> 16) & 1);          // round-nearest-even
  return (short)(u >> 16);
}

DEVINL void gl_lds16(const void* g, void* l) {
  __builtin_amdgcn_global_load_lds(
      (const __attribute__((address_space(1))) void*)g,
      (__attribute__((address_space(3))) void*)l, 16, 0, 0);
}

// C[m][n] = sum_k A[m][k]*B[n][k] (+ bias[m]).  A:[M][lda], B:[N][ldb] (both
// K-contiguous), C:[M][ldc].  Tile 128x128, BK=32, 256 thr = 4 waves (2x2),
// 16x16x32 bf16 MFMA.  m97-verified structure.
template <typename OutT, bool BIAS>
__global__ __launch_bounds__(256)
void gemm_nt(const short* __restrict__ A, long sA, int lda,
             const short* __restrict__ B, long sB, int ldb,
             OutT* __restrict__ C, long sC, int ldc,
             const float* __restrict__ bias, int K)
{
  A += (long)blockIdx.z * sA;
  B += (long)blockIdx.z * sB;
  C += (long)blockIdx.z * sC;

  __shared__ short As[128 * 32];
  __shared__ short Bs[128 * 32];

  const int t    = threadIdx.x;
  const int wave = t >> 6, lane = t & 63;
  const int quad = lane >> 4, l16 = lane & 15;
  const int m0 = blockIdx.y * 128, n0 = blockIdx.x * 128;
  const int lrow = t >> 2;            // 0..63
  const int lk8  = (t & 3) * 8;       // 0,8,16,24  (elements)
  const int arow = (wave >> 1) * 64, brow = (wave & 1) * 64;

  f32x4 acc[4][4];
#pragma unroll
  for (int i = 0; i < 4; ++i)
#pragma unroll
    for (int j = 0; j < 4; ++j) acc[i][j] = (f32x4){0.f, 0.f, 0.f, 0.f};

  for (int k0 = 0; k0 < K; k0 += 32) {
    // stage A/B tiles: LDS dst is wave-uniform base; lane i lands at base+i*16
#pragma unroll
    for (int s = 0; s < 2; ++s) {
      gl_lds16(A + (long)(m0 + s * 64 + lrow) * lda + k0 + lk8,
               (char*)As + s * 4096 + wave * 1024);
      gl_lds16(B + (long)(n0 + s * 64 + lrow) * ldb + k0 + lk8,
               (char*)Bs + s * 4096 + wave * 1024);
    }
    __syncthreads();   // drains vmcnt before barrier (compiler-emitted)

    bf16x8 af[4], bfr[4];
#pragma unroll
    for (int i = 0; i < 4; ++i)
      af[i] = *(const bf16x8*)&As[(arow + i * 16 + l16) * 32 + quad * 8];
#pragma unroll
    for (int i = 0; i < 4; ++i)
      bfr[i] = *(const bf16x8*)&Bs[(brow + i * 16 + l16) * 32 + quad * 8];

#pragma unroll
    for (int mi = 0; mi < 4; ++mi)
#pragma unroll
      for (int ni = 0; ni < 4; ++ni)
        acc[mi][ni] = __builtin_amdgcn_mfma_f32_16x16x32_bf16(
            af[mi], bfr[ni], acc[mi][ni], 0, 0, 0);
    __syncthreads();
  }

  // C/D layout (m89-verified): col = lane&15, row = quad*4 + reg
#pragma unroll
  for (int mi = 0; mi < 4; ++mi) {
#pragma unroll
    for (int ni = 0; ni < 4; ++ni) {
      const int col = n0 + brow + ni * 16 + l16;
#pragma unroll
      for (int r = 0; r < 4; ++r) {
        const int row = m0 + arow + mi * 16 + quad * 4 + r;
        float v = acc[mi][ni][r];
        if (BIAS) v += bias[row];
        if constexpr (std::is_same<OutT, float>::value)
          C[(long)row * ldc + col] = v;
        else
          C[(long)row * ldc + col] = f2bf(v);
      }
    }
  }
}

DEVINL float to_f(float v) { return v; }
DEVINL float to_f(short v) { return bf2f(v); }

// dst[Cc][R] = src[R][Cc]^T, with dtype convert.  block (32,8), 32x32 tiles.
template <typename InT, typename OutT>
__global__ void transpose_k(const InT* __restrict__ src, OutT* __restrict__ dst,
                            int R, int Cc, long ss, long ds)
{
  __shared__ float tile[32][33];
  src += (long)blockIdx.z * ss;
  dst += (long)blockIdx.z * ds;
  const int c0 = blockIdx.x * 32, r0 = blockIdx.y * 32;
  const int tx = threadIdx.x, ty = threadIdx.y;
#pragma unroll
  for (int i = 0; i < 4; ++i)
    tile[ty + i * 8][tx] = to_f(src[(long)(r0 + ty + i * 8) * Cc + c0 + tx]);
  __syncthreads();
#pragma unroll
  for (int i = 0; i < 4; ++i) {
    float v = tile[tx][ty + i * 8];
    if constexpr (std::is_same<OutT, float>::value)
      dst[(long)(c0 + ty + i * 8) * R + r0 + tx] = v;
    else
      dst[(long)(c0 + ty + i * 8) * R + r0 + tx] = f2bf(v);
  }
}

__global__ void cast_f32_bf16(const float* __restrict__ s, short* __restrict__ d, int n) {
  int i = blockIdx.x * 256 + threadIdx.x;
  if (i < n) d[i] = f2bf(s[i]);
}

// softmax over L=4096 for k rows, in-place in the qkv buffer (bf16).
// one block (256 thr) per (b,d) row; fp32 math, two-pass (max, sum-exp).
__global__ void softmax_rows(short* __restrict__ qkv) {
  const int L = 4096, Cc = 512;
  const int b = blockIdx.x >> 9, d = blockIdx.x & 511;
  short* p = qkv + (long)b * 3 * Cc * L + (long)Cc * L + (long)d * L;
  const int t = threadIdx.x, wave = t >> 6, lane = t & 63;

  float vals[16];
  float m = -1e30f;
#pragma unroll
  for (int i = 0; i < 16; ++i) {
    vals[i] = bf2f(p[t + i * 256]);
    m = fmaxf(m, vals[i]);
  }
  for (int off = 32; off; off >>= 1) m = fmaxf(m, __shfl_xor(m, off));
  __shared__ float redm[4], reds[4];
  if (lane == 0) redm[wave] = m;
  __syncthreads();
  m = fmaxf(fmaxf(redm[0], redm[1]), fmaxf(redm[2], redm[3]));

  float s = 0.f;
#pragma unroll
  for (int i = 0; i < 16; ++i) { vals[i] = __expf(vals[i] - m); s += vals[i]; }
  for (int off = 32; off; off >>= 1) s += __shfl_xor(s, off);
  if (lane == 0) reds[wave] = s;
  __syncthreads();
  s = reds[0] + reds[1] + reds[2] + reds[3];
  const float inv = 1.f / s;
#pragma unroll
  for (int i = 0; i < 16; ++i) p[t + i * 256] = f2bf(vals[i] * inv);
}

extern "C" void kernel_launch(void* const* d_in, const int* in_sizes, int n_in,
                              void* d_out, int out_size, void* d_ws, size_t ws_size,
                              hipStream_t stream) {
  // B=16, C=512, L=4096
  const float* x     = (const float*)d_in[0];
  const float* w_qkv = (const float*)d_in[1];
  const float* w_out = (const float*)d_in[2];
  const float* b_out = (const float*)d_in[3];
  float* out = (float*)d_out;

  const long CL  = (long)512 * 4096;       // 2097152
  const long LC  = CL;                     // xT / qT per-batch elements
  const long Q3  = 3 * CL;                 // qkv per-batch elements
  const long CC  = (long)512 * 512;        // 262144

  char* ws = (char*)d_ws;
  short* xT  = (short*)(ws);                        //  67,108,864 B
  short* qkv = (short*)(ws + 67108864);             // 201,326,592 B
  short* qT  = (short*)(ws + 268435456);            //  67,108,864 B
  short* ctx = (short*)(ws + 335544320);            //   8,388,608 B
  short* M2  = (short*)(ws + 343932928);            //   8,388,608 B
  short* wqb = (short*)(ws + 352321536);            //   1,572,864 B
  short* wob = (short*)(ws + 353894400);            //     524,288 B
  // total ws use: 354,418,688 B

  // weights -> bf16
  cast_f32_bf16<<<3072, 256, 0, stream>>>(w_qkv, wqb, 1536 * 512);
  cast_f32_bf16<<<1024, 256, 0, stream>>>(w_out, wob, 512 * 512);

  // xT[b][l][c] = bf16(x[b][c][l])
  transpose_k<float, short><<<dim3(128, 16, 16), dim3(32, 8), 0, stream>>>(
      x, xT, 512, 4096, CL, LC);

  // qkv[b][o][l] = sum_c wqb[o][c] * xT[b][l][c]   (M=1536,N=4096,K=512)
  gemm_nt<short, false><<<dim3(32, 12, 16), 256, 0, stream>>>(
      wqb, 0, 512, xT, LC, 512, qkv, (long)1536 * 4096, 4096, nullptr, 512);

  // softmax over l on the k third, in place
  softmax_rows<<<16 * 512, 256, 0, stream>>>(qkv);

  // qT[b][l][d] = q[b][d][l]
  transpose_k<short, short><<<dim3(128, 16, 16), dim3(32, 8), 0, stream>>>(
      qkv, qT, 512, 4096, Q3, LC);

  // ctx[b][d][e] = sum_n ksoft[b][d][n] * v[b][e][n]  (M=N=512,K=4096)
  gemm_nt<short, false><<<dim3(4, 4, 16), 256, 0, stream>>>(
      qkv + CL, Q3, 4096, qkv + 2 * CL, Q3, 4096, ctx, CC, 512, nullptr, 4096);

  // M2[b][o][d] = sum_e wob[o][e] * ctx[b][d][e]     (M=N=512,K=512)
  gemm_nt<short, false><<<dim3(4, 4, 16), 256, 0, stream>>>(
      wob, 0, 512, ctx, CC, 512, M2, CC, 512, nullptr, 512);

  // out[b][o][l] = sum_d M2[b][o][d] * qT[b][l][d] + b_out[o]  (fp32 out)
  gemm_nt<float, true><<<dim3(32, 4, 16), 256, 0, stream>>>(
      M2, CC, 512, qT, LC, 512, out, CL, 4096, b_out, 512);
}

// Round 2
// 604.155 us; speedup vs baseline: 1.0492x; 1.0492x over previous
//
#include <hip/hip_runtime.h>
#include <hip/hip_bf16.h>
#include <type_traits>

#define DEVINL __device__ __forceinline__

typedef float f32x4 __attribute__((ext_vector_type(4)));
typedef __bf16 bf16x8 __attribute__((ext_vector_type(8)));

DEVINL float bf2f(short s) {
  unsigned u = ((unsigned)(unsigned short)s) << 16;
  float f; __builtin_memcpy(&f, &u, 4); return f;
}
DEVINL short f2bf(float f) {
  unsigned u; __builtin_memcpy(&u, &f, 4);
  u += 0x7fff + ((u >> 16) & 1);          // round-nearest-even
  return (short)(u >> 16);
}

DEVINL void gl_lds16(const void* g, void* l) {
  __builtin_amdgcn_global_load_lds(
      (const __attribute__((address_space(1))) void*)g,
      (__attribute__((address_space(3))) void*)l, 16, 0, 0);
}

// C[m][n] = sum_k A[m][k]*B[n][k] (+ bias[m]).  A:[M][lda], B:[N][ldb] (both
// K-contiguous), C:[M][ldc].  Tile 128x128, BK=32, 256 thr = 4 waves (2x2),
// 16x16x32 bf16 MFMA.  m97-verified structure.
template <typename OutT, bool BIAS>
__global__ __launch_bounds__(256)
void gemm_nt(const short* __restrict__ A, long sA, int lda,
             const short* __restrict__ B, long sB, int ldb,
             OutT* __restrict__ C, long sC, int ldc,
             const float* __restrict__ bias, int K)
{
  A += (long)blockIdx.z * sA;
  B += (long)blockIdx.z * sB;
  C += (long)blockIdx.z * sC;

  __shared__ short As[128 * 32];
  __shared__ short Bs[128 * 32];

  const int t    = threadIdx.x;
  const int wave = t >> 6, lane = t & 63;
  const int quad = lane >> 4, l16 = lane & 15;
  const int m0 = blockIdx.y * 128, n0 = blockIdx.x * 128;
  const int lrow = t >> 2;            // 0..63
  const int lk8  = (t & 3) * 8;       // 0,8,16,24  (elements)
  const int arow = (wave >> 1) * 64, brow = (wave & 1) * 64;

  f32x4 acc[4][4];
#pragma unroll
  for (int i = 0; i < 4; ++i)
#pragma unroll
    for (int j = 0; j < 4; ++j) acc[i][j] = (f32x4){0.f, 0.f, 0.f, 0.f};

  for (int k0 = 0; k0 < K; k0 += 32) {
#pragma unroll
    for (int s = 0; s < 2; ++s) {
      gl_lds16(A + (long)(m0 + s * 64 + lrow) * lda + k0 + lk8,
               (char*)As + s * 4096 + wave * 1024);
      gl_lds16(B + (long)(n0 + s * 64 + lrow) * ldb + k0 + lk8,
               (char*)Bs + s * 4096 + wave * 1024);
    }
    __syncthreads();

    bf16x8 af[4], bfr[4];
#pragma unroll
    for (int i = 0; i < 4; ++i)
      af[i] = *(const bf16x8*)&As[(arow + i * 16 + l16) * 32 + quad * 8];
#pragma unroll
    for (int i = 0; i < 4; ++i)
      bfr[i] = *(const bf16x8*)&Bs[(brow + i * 16 + l16) * 32 + quad * 8];

#pragma unroll
    for (int mi = 0; mi < 4; ++mi)
#pragma unroll
      for (int ni = 0; ni < 4; ++ni)
        acc[mi][ni] = __builtin_amdgcn_mfma_f32_16x16x32_bf16(
            af[mi], bfr[ni], acc[mi][ni], 0, 0, 0);
    __syncthreads();
  }

  // C/D layout (m89-verified): col = lane&15, row = quad*4 + reg
#pragma unroll
  for (int mi = 0; mi < 4; ++mi) {
#pragma unroll
    for (int ni = 0; ni < 4; ++ni) {
      const int col = n0 + brow + ni * 16 + l16;
#pragma unroll
      for (int r = 0; r < 4; ++r) {
        const int row = m0 + arow + mi * 16 + quad * 4 + r;
        float v = acc[mi][ni][r];
        if (BIAS) v += bias[row];
        if constexpr (std::is_same<OutT, float>::value)
          C[(long)row * ldc + col] = v;
        else
          C[(long)row * ldc + col] = f2bf(v);
      }
    }
  }
}

// ctx split-K: ctxp[(s*16+b)][d][e] = sum_{n in chunk s} k[d][n]*v[e][n]
// M=N=512, K-chunk=1024, lda=ldb=4096, fp32 partials.  z = b*4 + s.
__global__ __launch_bounds__(256)
void gemm_ctx_sk(const short* __restrict__ kv, float* __restrict__ ctxp)
{
  const int b = blockIdx.z >> 2, s = blockIdx.z & 3;
  const short* A = kv + (long)b * 4194304;             // k part
  const short* B = kv + (long)b * 4194304 + 2097152;   // v part
  float* Cp = ctxp + (long)(s * 16 + b) * 262144;

  __shared__ short As[128 * 32];
  __shared__ short Bs[128 * 32];

  const int t    = threadIdx.x;
  const int wave = t >> 6, lane = t & 63;
  const int quad = lane >> 4, l16 = lane & 15;
  const int m0 = blockIdx.y * 128, n0 = blockIdx.x * 128;
  const int lrow = t >> 2;
  const int lk8  = (t & 3) * 8;
  const int arow = (wave >> 1) * 64, brow = (wave & 1) * 64;
  const int kbeg = s * 1024, kend = kbeg + 1024;

  f32x4 acc[4][4];
#pragma unroll
  for (int i = 0; i < 4; ++i)
#pragma unroll
    for (int j = 0; j < 4; ++j) acc[i][j] = (f32x4){0.f, 0.f, 0.f, 0.f};

  for (int k0 = kbeg; k0 < kend; k0 += 32) {
#pragma unroll
    for (int sb = 0; sb < 2; ++sb) {
      gl_lds16(A + (long)(m0 + sb * 64 + lrow) * 4096 + k0 + lk8,
               (char*)As + sb * 4096 + wave * 1024);
      gl_lds16(B + (long)(n0 + sb * 64 + lrow) * 4096 + k0 + lk8,
               (char*)Bs + sb * 4096 + wave * 1024);
    }
    __syncthreads();

    bf16x8 af[4], bfr[4];
#pragma unroll
    for (int i = 0; i < 4; ++i)
      af[i] = *(const bf16x8*)&As[(arow + i * 16 + l16) * 32 + quad * 8];
#pragma unroll
    for (int i = 0; i < 4; ++i)
      bfr[i] = *(const bf16x8*)&Bs[(brow + i * 16 + l16) * 32 + quad * 8];

#pragma unroll
    for (int mi = 0; mi < 4; ++mi)
#pragma unroll
      for (int ni = 0; ni < 4; ++ni)
        acc[mi][ni] = __builtin_amdgcn_mfma_f32_16x16x32_bf16(
            af[mi], bfr[ni], acc[mi][ni], 0, 0, 0);
    __syncthreads();
  }

#pragma unroll
  for (int mi = 0; mi < 4; ++mi)
#pragma unroll
    for (int ni = 0; ni < 4; ++ni) {
      const int col = n0 + brow + ni * 16 + l16;
#pragma unroll
      for (int r = 0; r < 4; ++r) {
        const int row = m0 + arow + mi * 16 + quad * 4 + r;
        Cp[(long)row * 512 + col] = acc[mi][ni][r];
      }
    }
}

// sum 4 fp32 split-K partials -> bf16 ctx.  4,194,304 elems, stride 4,194,304.
__global__ void reduce_ctx(const float* __restrict__ ctxp, short* __restrict__ ctx) {
  const long i = (long)blockIdx.x * 256 + threadIdx.x;
  float v = ctxp[i] + ctxp[i + 4194304] + ctxp[i + 2 * 4194304] + ctxp[i + 3 * 4194304];
  ctx[i] = f2bf(v);
}

DEVINL float to_f(float v) { return v; }
DEVINL float to_f(short v) { return bf2f(v); }

// dst[Cc][R] = src[R][Cc]^T, with dtype convert.  block (32,8), 32x32 tiles.
template <typename InT, typename OutT>
__global__ void transpose_k(const InT* __restrict__ src, OutT* __restrict__ dst,
                            int R, int Cc, long ss, long ds)
{
  __shared__ float tile[32][33];
  src += (long)blockIdx.z * ss;
  dst += (long)blockIdx.z * ds;
  const int c0 = blockIdx.x * 32, r0 = blockIdx.y * 32;
  const int tx = threadIdx.x, ty = threadIdx.y;
#pragma unroll
  for (int i = 0; i < 4; ++i)
    tile[ty + i * 8][tx] = to_f(src[(long)(r0 + ty + i * 8) * Cc + c0 + tx]);
  __syncthreads();
#pragma unroll
  for (int i = 0; i < 4; ++i) {
    float v = tile[tx][ty + i * 8];
    if constexpr (std::is_same<OutT, float>::value)
      dst[(long)(c0 + ty + i * 8) * R + r0 + tx] = v;
    else
      dst[(long)(c0 + ty + i * 8) * R + r0 + tx] = f2bf(v);
  }
}

// cast both weight matrices in one launch
__global__ void cast_weights(const float* __restrict__ wq, short* __restrict__ wqb,
                             const float* __restrict__ wo, short* __restrict__ wob) {
  const int i = blockIdx.x * 256 + threadIdx.x;
  if (i < 786432) wqb[i] = f2bf(wq[i]);
  else            wob[i - 786432] = f2bf(wo[i - 786432]);
}

// softmax over L=4096 on k rows (kv buffer rows 0..511 per batch), in place.
__global__ void softmax_rows(short* __restrict__ kv) {
  const int b = blockIdx.x >> 9, d = blockIdx.x & 511;
  short* p = kv + (long)b * 4194304 + (long)d * 4096;
  const int t = threadIdx.x, wave = t >> 6, lane = t & 63;

  float vals[16];
  float m = -1e30f;
#pragma unroll
  for (int i = 0; i < 16; ++i) {
    vals[i] = bf2f(p[t + i * 256]);
    m = fmaxf(m, vals[i]);
  }
  for (int off = 32; off; off >>= 1) m = fmaxf(m, __shfl_xor(m, off));
  __shared__ float redm[4], reds[4];
  if (lane == 0) redm[wave] = m;
  __syncthreads();
  m = fmaxf(fmaxf(redm[0], redm[1]), fmaxf(redm[2], redm[3]));

  float s = 0.f;
#pragma unroll
  for (int i = 0; i < 16; ++i) { vals[i] = __expf(vals[i] - m); s += vals[i]; }
  for (int off = 32; off; off >>= 1) s += __shfl_xor(s, off);
  if (lane == 0) reds[wave] = s;
  __syncthreads();
  s = reds[0] + reds[1] + reds[2] + reds[3];
  const float inv = 1.f / s;
#pragma unroll
  for (int i = 0; i < 16; ++i) p[t + i * 256] = f2bf(vals[i] * inv);
}

extern "C" void kernel_launch(void* const* d_in, const int* in_sizes, int n_in,
                              void* d_out, int out_size, void* d_ws, size_t ws_size,
                              hipStream_t stream) {
  // B=16, C=512, L=4096
  const float* x     = (const float*)d_in[0];
  const float* w_qkv = (const float*)d_in[1];
  const float* w_out = (const float*)d_in[2];
  const float* b_out = (const float*)d_in[3];
  float* out = (float*)d_out;

  const long CL = (long)512 * 4096;   // 2,097,152 elems per batch [C][L] or [L][C]
  const long KV = (long)1024 * 4096;  // 4,194,304 elems per batch (k+v)
  const long CC = (long)512 * 512;

  char* ws = (char*)d_ws;
  short* xT   = (short*)(ws);                 //  67,108,864 B  [b][l][c] bf16
  short* kv   = (short*)(ws + 67108864);      // 134,217,728 B  [b][o(2C)][l] bf16
  short* qT   = (short*)(ws + 201326592);     //  67,108,864 B  [b][l][c] bf16
  float* ctxp = (float*)(ws + 268435456);     //  67,108,864 B  [s][b][d][e] fp32
  short* ctx  = (short*)(ws + 335544320);     //   8,388,608 B  [b][d][e] bf16
  short* M2   = (short*)(ws + 343932928);     //   8,388,608 B  [b][o][d] bf16
  short* wqb  = (short*)(ws + 352321536);     //   1,572,864 B  bf16 w_qkv
  short* wob  = (short*)(ws + 353894400);     //     524,288 B  bf16 w_out
  // total ws use: 354,418,688 B

  cast_weights<<<4096, 256, 0, stream>>>(w_qkv, wqb, w_out, wob);

  // xT[b][l][c] = bf16(x[b][c][l])
  transpose_k<float, short><<<dim3(128, 16, 16), dim3(32, 8), 0, stream>>>(
      x, xT, 512, 4096, CL, CL);

  // qT[b][l][o] = sum_c xT[b][l][c] * wq[o][c]   (M=4096, N=512, K=512)
  gemm_nt<short, false><<<dim3(4, 32, 16), 256, 0, stream>>>(
      xT, CL, 512, wqb, 0, 512, qT, CL, 512, nullptr, 512);

  // kv[b][o][l] = sum_c wkv[o][c] * xT[b][l][c]  (M=1024, N=4096, K=512)
  gemm_nt<short, false><<<dim3(32, 8, 16), 256, 0, stream>>>(
      wqb + 512 * 512, 0, 512, xT, CL, 512, kv, KV, 4096, nullptr, 512);

  // softmax over l on k rows, in place
  softmax_rows<<<16 * 512, 256, 0, stream>>>(kv);

  // ctx split-K partials + reduce
  gemm_ctx_sk<<<dim3(4, 4, 64), 256, 0, stream>>>(kv, ctxp);
  reduce_ctx<<<16384, 256, 0, stream>>>(ctxp, ctx);

  // M2[b][o][d] = sum_e wob[o][e] * ctx[b][d][e]  (M=N=512, K=512)
  gemm_nt<short, false><<<dim3(4, 4, 16), 256, 0, stream>>>(
      wob, 0, 512, ctx, CC, 512, M2, CC, 512, nullptr, 512);

  // out[b][o][l] = sum_d M2[b][o][d] * qT[b][l][d] + b_out[o]  (fp32 out)
  gemm_nt<float, true><<<dim3(32, 4, 16), 256, 0, stream>>>(
      M2, CC, 512, qT, CL, 512, out, CL, 4096, b_out, 512);
}

// Round 3
// 562.422 us; speedup vs baseline: 1.1270x; 1.0742x over previous
//
#include <hip/hip_runtime.h>
#include <hip/hip_bf16.h>
#include <type_traits>

#define DEVINL __device__ __forceinline__

typedef float f32x4 __attribute__((ext_vector_type(4)));
typedef __bf16 bf16x8 __attribute__((ext_vector_type(8)));

DEVINL float bf2f(short s) {
  unsigned u = ((unsigned)(unsigned short)s) << 16;
  float f; __builtin_memcpy(&f, &u, 4); return f;
}
DEVINL short f2bf(float f) {
  unsigned u; __builtin_memcpy(&u, &f, 4);
  u += 0x7fff + ((u >> 16) & 1);          // round-nearest-even
  return (short)(u >> 16);
}

DEVINL void gl_lds16(const void* g, void* l) {
  __builtin_amdgcn_global_load_lds(
      (const __attribute__((address_space(1))) void*)g,
      (__attribute__((address_space(3))) void*)l, 16, 0, 0);
}

// Coalesced epilogue: acc tile -> LDS (32 KB) -> 16 B/lane stores with
// 256-512 B contiguous segments per wave-store.  R2 evidence: direct scattered
// stores capped both big GEMMs at ~1.15 TB/s write rate.
template <typename OutT, bool BIAS>
DEVINL void epilogue_store(f32x4 (&acc)[4][4], char* smem,
                           OutT* __restrict__ C, int ldc, int m0, int n0,
                           const float* __restrict__ bias, int t) {
  const int wave = t >> 6, lane = t & 63;
  const int quad = lane >> 4, l16 = lane & 15;
  const int arow = (wave >> 1) * 64, brow = (wave & 1) * 64;
  // K-loop's trailing __syncthreads already protects staging-LDS reuse.
  if constexpr (std::is_same<OutT, float>::value) {
    float* tile = (float*)smem;          // 64 x 128 fp32 = 32 KB per round
#pragma unroll
    for (int rnd = 0; rnd < 2; ++rnd) {
      if ((arow >> 6) == rnd) {          // waves 0,1 own rows 0..63; 2,3 own 64..127
#pragma unroll
        for (int mi = 0; mi < 4; ++mi)
#pragma unroll
          for (int ni = 0; ni < 4; ++ni) {
            const int col = brow + ni * 16 + l16;
#pragma unroll
            for (int r = 0; r < 4; ++r) {
              const int row = mi * 16 + quad * 4 + r;   // 0..63 local
              float v = acc[mi][ni][r];
              if (BIAS) v += bias[m0 + rnd * 64 + row];
              tile[row * 128 + col] = v;
            }
          }
      }
      __syncthreads();
      // 64 rows x 512 B; per instr 32 lanes cover one full 512 B row
#pragma unroll
      for (int i = 0; i < 8; ++i) {
        const int row = wave * 16 + i * 2 + (lane >> 5);  // 0..63
        const int cf  = (lane & 31) * 4;                   // float col 0..124
        f32x4 v = *(f32x4*)&tile[row * 128 + cf];
        *(f32x4*)&C[(long)(m0 + rnd * 64 + row) * ldc + n0 + cf] = v;
      }
      __syncthreads();
    }
  } else {
    short* tile = (short*)smem;          // 128 x 128 bf16 = 32 KB
#pragma unroll
    for (int mi = 0; mi < 4; ++mi)
#pragma unroll
      for (int ni = 0; ni < 4; ++ni) {
        const int col = brow + ni * 16 + l16;
#pragma unroll
        for (int r = 0; r < 4; ++r) {
          const int row = arow + mi * 16 + quad * 4 + r;
          float v = acc[mi][ni][r];
          if (BIAS) v += bias[m0 + row];
          tile[row * 128 + col] = f2bf(v);
        }
      }
    __syncthreads();
    // 128 rows x 256 B; per instr 16 lanes cover one full 256 B row
#pragma unroll
    for (int i = 0; i < 8; ++i) {
      const int row = wave * 32 + i * 4 + (lane >> 4);    // 0..127
      const int cs  = l16 * 8;                             // short col
      int4 v = *(int4*)&tile[row * 128 + cs];
      *(int4*)&C[(long)(m0 + row) * ldc + n0 + cs] = v;
    }
  }
}

// C[m][n] = sum_k A[m][k]*B[n][k] (+ bias[m]).  A:[M][lda], B:[N][ldb] (both
// K-contiguous), C:[M][ldc].  128x128 tile, BK=32, 4 waves, 16x16x32 MFMA.
template <typename OutT, bool BIAS>
__global__ __launch_bounds__(256)
void gemm_nt(const short* __restrict__ A, long sA, int lda,
             const short* __restrict__ B, long sB, int ldb,
             OutT* __restrict__ C, long sC, int ldc,
             const float* __restrict__ bias, int K)
{
  A += (long)blockIdx.z * sA;
  B += (long)blockIdx.z * sB;
  C += (long)blockIdx.z * sC;

  __shared__ char smem[32768];           // staging 16 KB; epilogue 32 KB
  short* As = (short*)smem;
  short* Bs = (short*)(smem + 8192);

  const int t    = threadIdx.x;
  const int wave = t >> 6, lane = t & 63;
  const int quad = lane >> 4, l16 = lane & 15;
  const int m0 = blockIdx.y * 128, n0 = blockIdx.x * 128;
  const int lrow = t >> 2;
  const int lk8  = (t & 3) * 8;
  const int arow = (wave >> 1) * 64, brow = (wave & 1) * 64;

  f32x4 acc[4][4];
#pragma unroll
  for (int i = 0; i < 4; ++i)
#pragma unroll
    for (int j = 0; j < 4; ++j) acc[i][j] = (f32x4){0.f, 0.f, 0.f, 0.f};

  for (int k0 = 0; k0 < K; k0 += 32) {
#pragma unroll
    for (int s = 0; s < 2; ++s) {
      gl_lds16(A + (long)(m0 + s * 64 + lrow) * lda + k0 + lk8,
               (char*)As + s * 4096 + wave * 1024);
      gl_lds16(B + (long)(n0 + s * 64 + lrow) * ldb + k0 + lk8,
               (char*)Bs + s * 4096 + wave * 1024);
    }
    __syncthreads();

    bf16x8 af[4], bfr[4];
#pragma unroll
    for (int i = 0; i < 4; ++i)
      af[i] = *(const bf16x8*)&As[(arow + i * 16 + l16) * 32 + quad * 8];
#pragma unroll
    for (int i = 0; i < 4; ++i)
      bfr[i] = *(const bf16x8*)&Bs[(brow + i * 16 + l16) * 32 + quad * 8];

#pragma unroll
    for (int mi = 0; mi < 4; ++mi)
#pragma unroll
      for (int ni = 0; ni < 4; ++ni)
        acc[mi][ni] = __builtin_amdgcn_mfma_f32_16x16x32_bf16(
            af[mi], bfr[ni], acc[mi][ni], 0, 0, 0);
    __syncthreads();
  }

  epilogue_store<OutT, BIAS>(acc, smem, C, ldc, m0, n0, bias, t);
}

// ctx split-K: ctxp[(s*16+b)][d][e] = sum_{n in chunk s} k[d][n]*v[e][n]
__global__ __launch_bounds__(256)
void gemm_ctx_sk(const short* __restrict__ kv, float* __restrict__ ctxp)
{
  const int b = blockIdx.z >> 2, s = blockIdx.z & 3;
  const short* A = kv + (long)b * 4194304;             // k
  const short* B = kv + (long)b * 4194304 + 2097152;   // v
  float* Cp = ctxp + (long)(s * 16 + b) * 262144;

  __shared__ char smem[32768];
  short* As = (short*)smem;
  short* Bs = (short*)(smem + 8192);

  const int t    = threadIdx.x;
  const int wave = t >> 6, lane = t & 63;
  const int quad = lane >> 4, l16 = lane & 15;
  const int m0 = blockIdx.y * 128, n0 = blockIdx.x * 128;
  const int lrow = t >> 2;
  const int lk8  = (t & 3) * 8;
  const int arow = (wave >> 1) * 64, brow = (wave & 1) * 64;
  const int kbeg = s * 1024, kend = kbeg + 1024;

  f32x4 acc[4][4];
#pragma unroll
  for (int i = 0; i < 4; ++i)
#pragma unroll
    for (int j = 0; j < 4; ++j) acc[i][j] = (f32x4){0.f, 0.f, 0.f, 0.f};

  for (int k0 = kbeg; k0 < kend; k0 += 32) {
#pragma unroll
    for (int sb = 0; sb < 2; ++sb) {
      gl_lds16(A + (long)(m0 + sb * 64 + lrow) * 4096 + k0 + lk8,
               (char*)As + sb * 4096 + wave * 1024);
      gl_lds16(B + (long)(n0 + sb * 64 + lrow) * 4096 + k0 + lk8,
               (char*)Bs + sb * 4096 + wave * 1024);
    }
    __syncthreads();

    bf16x8 af[4], bfr[4];
#pragma unroll
    for (int i = 0; i < 4; ++i)
      af[i] = *(const bf16x8*)&As[(arow + i * 16 + l16) * 32 + quad * 8];
#pragma unroll
    for (int i = 0; i < 4; ++i)
      bfr[i] = *(const bf16x8*)&Bs[(brow + i * 16 + l16) * 32 + quad * 8];

#pragma unroll
    for (int mi = 0; mi < 4; ++mi)
#pragma unroll
      for (int ni = 0; ni < 4; ++ni)
        acc[mi][ni] = __builtin_amdgcn_mfma_f32_16x16x32_bf16(
            af[mi], bfr[ni], acc[mi][ni], 0, 0, 0);
    __syncthreads();
  }

  epilogue_store<float, false>(acc, smem, Cp, 512, m0, n0, nullptr, t);
}

// sum 4 fp32 split-K partials -> bf16 ctx, float4-vectorized
__global__ void reduce_ctx(const float* __restrict__ ctxp, short* __restrict__ ctx) {
  const long i = ((long)blockIdx.x * 256 + threadIdx.x) * 4;
  f32x4 a = *(const f32x4*)&ctxp[i];
  f32x4 b = *(const f32x4*)&ctxp[i + 4194304];
  f32x4 c = *(const f32x4*)&ctxp[i + 2 * 4194304];
  f32x4 d = *(const f32x4*)&ctxp[i + 3 * 4194304];
  short o[4];
#pragma unroll
  for (int j = 0; j < 4; ++j) o[j] = f2bf(a[j] + b[j] + c[j] + d[j]);
  *(long*)&ctx[i] = *(long*)o;
}

DEVINL float to_f(float v) { return v; }
DEVINL float to_f(short v) { return bf2f(v); }

// dst[Cc][R] = src[R][Cc]^T, with dtype convert.  block (32,8), 32x32 tiles.
template <typename InT, typename OutT>
__global__ void transpose_k(const InT* __restrict__ src, OutT* __restrict__ dst,
                            int R, int Cc, long ss, long ds)
{
  __shared__ float tile[32][33];
  src += (long)blockIdx.z * ss;
  dst += (long)blockIdx.z * ds;
  const int c0 = blockIdx.x * 32, r0 = blockIdx.y * 32;
  const int tx = threadIdx.x, ty = threadIdx.y;
#pragma unroll
  for (int i = 0; i < 4; ++i)
    tile[ty + i * 8][tx] = to_f(src[(long)(r0 + ty + i * 8) * Cc + c0 + tx]);
  __syncthreads();
#pragma unroll
  for (int i = 0; i < 4; ++i) {
    float v = tile[tx][ty + i * 8];
    if constexpr (std::is_same<OutT, float>::value)
      dst[(long)(c0 + ty + i * 8) * R + r0 + tx] = v;
    else
      dst[(long)(c0 + ty + i * 8) * R + r0 + tx] = f2bf(v);
  }
}

__global__ void cast_weights(const float* __restrict__ wq, short* __restrict__ wqb,
                             const float* __restrict__ wo, short* __restrict__ wob) {
  const int i = blockIdx.x * 256 + threadIdx.x;
  if (i < 786432) wqb[i] = f2bf(wq[i]);
  else            wob[i - 786432] = f2bf(wo[i - 786432]);
}

// softmax over L=4096 on k rows, in place, bf16x8-vectorized.
__global__ void softmax_rows(short* __restrict__ kv) {
  const int b = blockIdx.x >> 9, d = blockIdx.x & 511;
  short* p = kv + (long)b * 4194304 + (long)d * 4096;
  const int t = threadIdx.x, wave = t >> 6, lane = t & 63;

  short v16[16];
  *(int4*)&v16[0] = *(const int4*)&p[t * 8];
  *(int4*)&v16[8] = *(const int4*)&p[2048 + t * 8];

  float vals[16];
  float m = -1e30f;
#pragma unroll
  for (int i = 0; i < 16; ++i) {
    vals[i] = bf2f(v16[i]);
    m = fmaxf(m, vals[i]);
  }
  for (int off = 32; off; off >>= 1) m = fmaxf(m, __shfl_xor(m, off));
  __shared__ float redm[4], reds[4];
  if (lane == 0) redm[wave] = m;
  __syncthreads();
  m = fmaxf(fmaxf(redm[0], redm[1]), fmaxf(redm[2], redm[3]));

  float s = 0.f;
#pragma unroll
  for (int i = 0; i < 16; ++i) { vals[i] = __expf(vals[i] - m); s += vals[i]; }
  for (int off = 32; off; off >>= 1) s += __shfl_xor(s, off);
  if (lane == 0) reds[wave] = s;
  __syncthreads();
  s = reds[0] + reds[1] + reds[2] + reds[3];
  const float inv = 1.f / s;
#pragma unroll
  for (int i = 0; i < 16; ++i) v16[i] = f2bf(vals[i] * inv);
  *(int4*)&p[t * 8] = *(int4*)&v16[0];
  *(int4*)&p[2048 + t * 8] = *(int4*)&v16[8];
}

extern "C" void kernel_launch(void* const* d_in, const int* in_sizes, int n_in,
                              void* d_out, int out_size, void* d_ws, size_t ws_size,
                              hipStream_t stream) {
  // B=16, C=512, L=4096
  const float* x     = (const float*)d_in[0];
  const float* w_qkv = (const float*)d_in[1];
  const float* w_out = (const float*)d_in[2];
  const float* b_out = (const float*)d_in[3];
  float* out = (float*)d_out;

  const long CL = (long)512 * 4096;   // per-batch [C][L] / [L][C]
  const long KV = (long)1024 * 4096;  // per-batch k+v
  const long CC = (long)512 * 512;

  char* ws = (char*)d_ws;
  short* xT   = (short*)(ws);                 //  67,108,864 B  [b][l][c] bf16
  short* kv   = (short*)(ws + 67108864);      // 134,217,728 B  [b][2C][l] bf16
  float* ctxp = (float*)(ws + 201326592);     //  67,108,864 B  [s][b][d][e] fp32
  short* ctx  = (short*)(ws + 268435456);     //   8,388,608 B  [b][d][e] bf16
  short* M2   = (short*)(ws + 276824064);     //   8,388,608 B  [b][o][d] bf16
  short* M3   = (short*)(ws + 285212672);     //   8,388,608 B  [b][o][c] bf16
  short* wqb  = (short*)(ws + 293601280);     //   1,572,864 B  bf16 w_qkv
  short* wob  = (short*)(ws + 295174144);     //     524,288 B  bf16 w_out
  short* wqT  = (short*)(ws + 295698432);     //     524,288 B  bf16 w_q^T [c][d]
  // total ws use: 296,222,720 B

  cast_weights<<<4096, 256, 0, stream>>>(w_qkv, wqb, w_out, wob);

  // wqT[c][d] = bf16(w_q[d][c])  (w_q = first 512 rows of w_qkv)
  transpose_k<float, short><<<dim3(16, 16, 1), dim3(32, 8), 0, stream>>>(
      w_qkv, wqT, 512, 512, 0, 0);

  // xT[b][l][c] = bf16(x[b][c][l])
  transpose_k<float, short><<<dim3(128, 16, 16), dim3(32, 8), 0, stream>>>(
      x, xT, 512, 4096, CL, CL);

  // kv[b][o][l] = sum_c wkv[o][c] * xT[b][l][c]  (M=1024, N=4096, K=512)
  gemm_nt<short, false><<<dim3(32, 8, 16), 256, 0, stream>>>(
      wqb + 512 * 512, 0, 512, xT, CL, 512, kv, KV, 4096, nullptr, 512);

  // softmax over l on k rows, in place
  softmax_rows<<<16 * 512, 256, 0, stream>>>(kv);

  // ctx split-K partials + reduce
  gemm_ctx_sk<<<dim3(4, 4, 64), 256, 0, stream>>>(kv, ctxp);
  reduce_ctx<<<4096, 256, 0, stream>>>(ctxp, ctx);

  // M2[b][o][d] = sum_e wob[o][e] * ctx[b][d][e]  (M=N=512, K=512)
  gemm_nt<short, false><<<dim3(4, 4, 16), 256, 0, stream>>>(
      wob, 0, 512, ctx, CC, 512, M2, CC, 512, nullptr, 512);

  // M3[b][o][c] = sum_d M2[b][o][d] * wqT[c][d]   (M=N=512, K=512)
  gemm_nt<short, false><<<dim3(4, 4, 16), 256, 0, stream>>>(
      M2, CC, 512, wqT, 0, 512, M3, CC, 512, nullptr, 512);

  // out[b][o][l] = sum_c M3[b][o][c] * xT[b][l][c] + b_out[o]  (fp32 out)
  gemm_nt<float, true><<<dim3(32, 4, 16), 256, 0, stream>>>(
      M3, CC, 512, xT, CL, 512, out, CL, 4096, b_out, 512);
}

// Round 4
// 533.194 us; speedup vs baseline: 1.1888x; 1.0548x over previous
//
#include <hip/hip_runtime.h>
#include <hip/hip_bf16.h>
#include <type_traits>

#define DEVINL __device__ __forceinline__

typedef float f32x4 __attribute__((ext_vector_type(4)));
typedef __bf16 bf16x8 __attribute__((ext_vector_type(8)));

DEVINL float bf2f(short s) {
  unsigned u = ((unsigned)(unsigned short)s) << 16;
  float f; __builtin_memcpy(&f, &u, 4); return f;
}
DEVINL short f2bf(float f) {
  unsigned u; __builtin_memcpy(&u, &f, 4);
  u += 0x7fff + ((u >> 16) & 1);          // round-nearest-even
  return (short)(u >> 16);
}

DEVINL void gl_lds16(const void* g, void* l) {
  __builtin_amdgcn_global_load_lds(
      (const __attribute__((address_space(1))) void*)g,
      (__attribute__((address_space(3))) void*)l, 16, 0, 0);
}

// Coalesced epilogue via 32 KB LDS remap (R3: neutral vs scattered stores, but
// keep — it frees the write path; bottleneck is loop structure/occupancy).
template <typename OutT, bool BIAS>
DEVINL void epilogue_store(f32x4 (&acc)[4][4], char* smem,
                           OutT* __restrict__ C, int ldc, int m0, int n0,
                           const float* __restrict__ bias, int t) {
  const int wave = t >> 6, lane = t & 63;
  const int quad = lane >> 4, l16 = lane & 15;
  const int arow = (wave >> 1) * 64, brow = (wave & 1) * 64;
  if constexpr (std::is_same<OutT, float>::value) {
    float* tile = (float*)smem;          // 64 x 128 fp32 per round
#pragma unroll
    for (int rnd = 0; rnd < 2; ++rnd) {
      if ((arow >> 6) == rnd) {
#pragma unroll
        for (int mi = 0; mi < 4; ++mi)
#pragma unroll
          for (int ni = 0; ni < 4; ++ni) {
            const int col = brow + ni * 16 + l16;
#pragma unroll
            for (int r = 0; r < 4; ++r) {
              const int row = mi * 16 + quad * 4 + r;
              float v = acc[mi][ni][r];
              if (BIAS) v += bias[m0 + rnd * 64 + row];
              tile[row * 128 + col] = v;
            }
          }
      }
      __syncthreads();
#pragma unroll
      for (int i = 0; i < 8; ++i) {
        const int row = wave * 16 + i * 2 + (lane >> 5);
        const int cf  = (lane & 31) * 4;
        f32x4 v = *(f32x4*)&tile[row * 128 + cf];
        *(f32x4*)&C[(long)(m0 + rnd * 64 + row) * ldc + n0 + cf] = v;
      }
      __syncthreads();
    }
  } else {
    short* tile = (short*)smem;          // 128 x 128 bf16
#pragma unroll
    for (int mi = 0; mi < 4; ++mi)
#pragma unroll
      for (int ni = 0; ni < 4; ++ni) {
        const int col = brow + ni * 16 + l16;
#pragma unroll
        for (int r = 0; r < 4; ++r) {
          const int row = arow + mi * 16 + quad * 4 + r;
          float v = acc[mi][ni][r];
          if (BIAS) v += bias[m0 + row];
          tile[row * 128 + col] = f2bf(v);
        }
      }
    __syncthreads();
#pragma unroll
    for (int i = 0; i < 8; ++i) {
      const int row = wave * 32 + i * 4 + (lane >> 4);
      const int cs  = l16 * 8;
      int4 v = *(int4*)&tile[row * 128 + cs];
      *(int4*)&C[(long)(m0 + row) * ldc + n0 + cs] = v;
    }
  }
}

// C[m][n] = sum_k A[m][k]*B[n][k] (+ bias[m]).  128x128 tile, BK=32, 4 waves.
// launch_bounds(256,4): regs were 68+64=132, 4 over the 128 occupancy step
// (m69) -> ask allocator for <=128 to get 4 blocks/CU (16 waves/CU).
template <typename OutT, bool BIAS>
__global__ __launch_bounds__(256, 4)
void gemm_nt(const short* __restrict__ A, long sA, int lda,
             const short* __restrict__ B, long sB, int ldb,
             OutT* __restrict__ C, long sC, int ldc,
             const float* __restrict__ bias, int K)
{
  A += (long)blockIdx.z * sA;
  B += (long)blockIdx.z * sB;
  C += (long)blockIdx.z * sC;

  __shared__ char smem[32768];           // staging 16 KB; epilogue 32 KB
  short* As = (short*)smem;
  short* Bs = (short*)(smem + 8192);

  const int t    = threadIdx.x;
  const int wave = t >> 6, lane = t & 63;
  const int quad = lane >> 4, l16 = lane & 15;
  const int m0 = blockIdx.y * 128, n0 = blockIdx.x * 128;
  const int lrow = t >> 2;
  const int lk8  = (t & 3) * 8;
  const int arow = (wave >> 1) * 64, brow = (wave & 1) * 64;

  f32x4 acc[4][4];
#pragma unroll
  for (int i = 0; i < 4; ++i)
#pragma unroll
    for (int j = 0; j < 4; ++j) acc[i][j] = (f32x4){0.f, 0.f, 0.f, 0.f};

  for (int k0 = 0; k0 < K; k0 += 32) {
#pragma unroll
    for (int s = 0; s < 2; ++s) {
      gl_lds16(A + (long)(m0 + s * 64 + lrow) * lda + k0 + lk8,
               (char*)As + s * 4096 + wave * 1024);
      gl_lds16(B + (long)(n0 + s * 64 + lrow) * ldb + k0 + lk8,
               (char*)Bs + s * 4096 + wave * 1024);
    }
    __syncthreads();

    bf16x8 af[4], bfr[4];
#pragma unroll
    for (int i = 0; i < 4; ++i)
      af[i] = *(const bf16x8*)&As[(arow + i * 16 + l16) * 32 + quad * 8];
#pragma unroll
    for (int i = 0; i < 4; ++i)
      bfr[i] = *(const bf16x8*)&Bs[(brow + i * 16 + l16) * 32 + quad * 8];

#pragma unroll
    for (int mi = 0; mi < 4; ++mi)
#pragma unroll
      for (int ni = 0; ni < 4; ++ni)
        acc[mi][ni] = __builtin_amdgcn_mfma_f32_16x16x32_bf16(
            af[mi], bfr[ni], acc[mi][ni], 0, 0, 0);
    __syncthreads();
  }

  epilogue_store<OutT, BIAS>(acc, smem, C, ldc, m0, n0, bias, t);
}

// split-K NT GEMM, M=N=512, K=4096 in 4 chunks of 1024, fp32 partials.
// z = b*4 + s.  A,B per-batch stride 2097152, lda=ldb=4096.
__global__ __launch_bounds__(256, 4)
void gemm_sk(const short* __restrict__ Ab, const short* __restrict__ Bb,
             float* __restrict__ Cp)
{
  const int b = blockIdx.z >> 2, s = blockIdx.z & 3;
  const short* A = Ab + (long)b * 2097152;
  const short* B = Bb + (long)b * 2097152;
  float* C = Cp + (long)(s * 16 + b) * 262144;

  __shared__ char smem[32768];
  short* As = (short*)smem;
  short* Bs = (short*)(smem + 8192);

  const int t    = threadIdx.x;
  const int wave = t >> 6, lane = t & 63;
  const int quad = lane >> 4, l16 = lane & 15;
  const int m0 = blockIdx.y * 128, n0 = blockIdx.x * 128;
  const int lrow = t >> 2;
  const int lk8  = (t & 3) * 8;
  const int arow = (wave >> 1) * 64, brow = (wave & 1) * 64;
  const int kbeg = s * 1024, kend = kbeg + 1024;

  f32x4 acc[4][4];
#pragma unroll
  for (int i = 0; i < 4; ++i)
#pragma unroll
    for (int j = 0; j < 4; ++j) acc[i][j] = (f32x4){0.f, 0.f, 0.f, 0.f};

  for (int k0 = kbeg; k0 < kend; k0 += 32) {
#pragma unroll
    for (int sb = 0; sb < 2; ++sb) {
      gl_lds16(A + (long)(m0 + sb * 64 + lrow) * 4096 + k0 + lk8,
               (char*)As + sb * 4096 + wave * 1024);
      gl_lds16(B + (long)(n0 + sb * 64 + lrow) * 4096 + k0 + lk8,
               (char*)Bs + sb * 4096 + wave * 1024);
    }
    __syncthreads();

    bf16x8 af[4], bfr[4];
#pragma unroll
    for (int i = 0; i < 4; ++i)
      af[i] = *(const bf16x8*)&As[(arow + i * 16 + l16) * 32 + quad * 8];
#pragma unroll
    for (int i = 0; i < 4; ++i)
      bfr[i] = *(const bf16x8*)&Bs[(brow + i * 16 + l16) * 32 + quad * 8];

#pragma unroll
    for (int mi = 0; mi < 4; ++mi)
#pragma unroll
      for (int ni = 0; ni < 4; ++ni)
        acc[mi][ni] = __builtin_amdgcn_mfma_f32_16x16x32_bf16(
            af[mi], bfr[ni], acc[mi][ni], 0, 0, 0);
    __syncthreads();
  }

  epilogue_store<float, false>(acc, smem, C, 512, m0, n0, nullptr, t);
}

// sum 4 fp32 split-K partials -> bf16, float4-vectorized
__global__ void reduce_sk(const float* __restrict__ p, short* __restrict__ o) {
  const long i = ((long)blockIdx.x * 256 + threadIdx.x) * 4;
  f32x4 a = *(const f32x4*)&p[i];
  f32x4 b = *(const f32x4*)&p[i + 4194304];
  f32x4 c = *(const f32x4*)&p[i + 2 * 4194304];
  f32x4 d = *(const f32x4*)&p[i + 3 * 4194304];
  short r[4];
#pragma unroll
  for (int j = 0; j < 4; ++j) r[j] = f2bf(a[j] + b[j] + c[j] + d[j]);
  *(long*)&o[i] = *(long*)r;
}

// xT[b][l][c] = bf16(x[b][c][l]);  xb[b][c][l] = bf16(x[b][c][l])
__global__ void transpose_cast(const float* __restrict__ x,
                               short* __restrict__ xT, short* __restrict__ xb)
{
  __shared__ float tile[32][33];
  x  += (long)blockIdx.z * 2097152;
  xT += (long)blockIdx.z * 2097152;
  xb += (long)blockIdx.z * 2097152;
  const int l0 = blockIdx.x * 32, c0 = blockIdx.y * 32;
  const int tx = threadIdx.x, ty = threadIdx.y;
#pragma unroll
  for (int i = 0; i < 4; ++i) {
    float v = x[(long)(c0 + ty + i * 8) * 4096 + l0 + tx];
    tile[ty + i * 8][tx] = v;
    xb[(long)(c0 + ty + i * 8) * 4096 + l0 + tx] = f2bf(v);
  }
  __syncthreads();
#pragma unroll
  for (int i = 0; i < 4; ++i)
    xT[(long)(l0 + ty + i * 8) * 512 + c0 + tx] = f2bf(tile[tx][ty + i * 8]);
}

DEVINL float to_f(float v) { return v; }
DEVINL float to_f(short v) { return bf2f(v); }

template <typename InT, typename OutT>
__global__ void transpose_k(const InT* __restrict__ src, OutT* __restrict__ dst,
                            int R, int Cc, long ss, long ds)
{
  __shared__ float tile[32][33];
  src += (long)blockIdx.z * ss;
  dst += (long)blockIdx.z * ds;
  const int c0 = blockIdx.x * 32, r0 = blockIdx.y * 32;
  const int tx = threadIdx.x, ty = threadIdx.y;
#pragma unroll
  for (int i = 0; i < 4; ++i)
    tile[ty + i * 8][tx] = to_f(src[(long)(r0 + ty + i * 8) * Cc + c0 + tx]);
  __syncthreads();
#pragma unroll
  for (int i = 0; i < 4; ++i) {
    float v = tile[tx][ty + i * 8];
    if constexpr (std::is_same<OutT, float>::value)
      dst[(long)(c0 + ty + i * 8) * R + r0 + tx] = v;
    else
      dst[(long)(c0 + ty + i * 8) * R + r0 + tx] = f2bf(v);
  }
}

__global__ void cast_weights(const float* __restrict__ wq, short* __restrict__ wqb,
                             const float* __restrict__ wo, short* __restrict__ wob) {
  const int i = blockIdx.x * 256 + threadIdx.x;
  if (i < 786432) wqb[i] = f2bf(wq[i]);
  else            wob[i - 786432] = f2bf(wo[i - 786432]);
}

// softmax over L=4096 on k rows [b][512][4096], in place, bf16x8-vectorized.
__global__ void softmax_rows(short* __restrict__ k) {
  const int b = blockIdx.x >> 9, d = blockIdx.x & 511;
  short* p = k + (long)b * 2097152 + (long)d * 4096;
  const int t = threadIdx.x, wave = t >> 6, lane = t & 63;

  short v16[16];
  *(int4*)&v16[0] = *(const int4*)&p[t * 8];
  *(int4*)&v16[8] = *(const int4*)&p[2048 + t * 8];

  float vals[16];
  float m = -1e30f;
#pragma unroll
  for (int i = 0; i < 16; ++i) {
    vals[i] = bf2f(v16[i]);
    m = fmaxf(m, vals[i]);
  }
  for (int off = 32; off; off >>= 1) m = fmaxf(m, __shfl_xor(m, off));
  __shared__ float redm[4], reds[4];
  if (lane == 0) redm[wave] = m;
  __syncthreads();
  m = fmaxf(fmaxf(redm[0], redm[1]), fmaxf(redm[2], redm[3]));

  float s = 0.f;
#pragma unroll
  for (int i = 0; i < 16; ++i) { vals[i] = __expf(vals[i] - m); s += vals[i]; }
  for (int off = 32; off; off >>= 1) s += __shfl_xor(s, off);
  if (lane == 0) reds[wave] = s;
  __syncthreads();
  s = reds[0] + reds[1] + reds[2] + reds[3];
  const float inv = 1.f / s;
#pragma unroll
  for (int i = 0; i < 16; ++i) v16[i] = f2bf(vals[i] * inv);
  *(int4*)&p[t * 8] = *(int4*)&v16[0];
  *(int4*)&p[2048 + t * 8] = *(int4*)&v16[8];
}

extern "C" void kernel_launch(void* const* d_in, const int* in_sizes, int n_in,
                              void* d_out, int out_size, void* d_ws, size_t ws_size,
                              hipStream_t stream) {
  // B=16, C=512, L=4096
  const float* x     = (const float*)d_in[0];
  const float* w_qkv = (const float*)d_in[1];
  const float* w_out = (const float*)d_in[2];
  const float* b_out = (const float*)d_in[3];
  float* out = (float*)d_out;

  const long CL = (long)512 * 4096;   // 2,097,152 per-batch elems
  const long CC = (long)512 * 512;

  char* ws = (char*)d_ws;
  short* xT  = (short*)(ws);                 //  67,108,864 B  [b][l][c]
  short* xb  = (short*)(ws + 67108864);      //  67,108,864 B  [b][c][l]
  short* kbf = (short*)(ws + 134217728);     //  67,108,864 B  [b][d][l]
  float* Pp  = (float*)(ws + 201326592);     //  67,108,864 B  [s][b][d][c] fp32
  short* P   = (short*)(ws + 268435456);     //   8,388,608 B  [b][d][c]
  short* ctx = (short*)(ws + 276824064);     //   8,388,608 B  [b][d][e]
  short* M2  = (short*)(ws + 285212672);     //   8,388,608 B  [b][o][d]
  short* M3  = (short*)(ws + 293601280);     //   8,388,608 B  [b][o][c]
  short* wqb = (short*)(ws + 301989888);     //   1,572,864 B
  short* wob = (short*)(ws + 303562752);     //     524,288 B
  short* wqT = (short*)(ws + 304087040);     //     524,288 B  w_q^T [c][d]
  // total ws use: 304,611,328 B

  cast_weights<<<4096, 256, 0, stream>>>(w_qkv, wqb, w_out, wob);

  // wqT[c][d] = bf16(w_q[d][c])
  transpose_k<float, short><<<dim3(16, 16, 1), dim3(32, 8), 0, stream>>>(
      w_qkv, wqT, 512, 512, 0, 0);

  // xT + xb in one pass over x
  transpose_cast<<<dim3(128, 16, 16), dim3(32, 8), 0, stream>>>(x, xT, xb);

  // k[b][d][l] = sum_c w_k[d][c] * xT[b][l][c]   (M=512, N=4096, K=512)
  gemm_nt<short, false><<<dim3(32, 4, 16), 256, 0, stream>>>(
      wqb + 512 * 512, 0, 512, xT, CL, 512, kbf, CL, 4096, nullptr, 512);

  // softmax over l, in place
  softmax_rows<<<16 * 512, 256, 0, stream>>>(kbf);

  // P[b][d][c] = sum_l k_s[d][l] * xb[c][l]   (M=N=512, K=4096, split-K)
  gemm_sk<<<dim3(4, 4, 64), 256, 0, stream>>>(kbf, xb, Pp);
  reduce_sk<<<4096, 256, 0, stream>>>(Pp, P);

  // ctx[b][d][e] = sum_c P[d][c] * w_v[e][c]   (M=N=512, K=512)
  gemm_nt<short, false><<<dim3(4, 4, 16), 256, 0, stream>>>(
      P, CC, 512, wqb + 2 * 512 * 512, 0, 512, ctx, CC, 512, nullptr, 512);

  // M2[b][o][d] = sum_e wob[o][e] * ctx[d][e]  (M=N=512, K=512)
  gemm_nt<short, false><<<dim3(4, 4, 16), 256, 0, stream>>>(
      wob, 0, 512, ctx, CC, 512, M2, CC, 512, nullptr, 512);

  // M3[b][o][c] = sum_d M2[o][d] * wqT[c][d]   (M=N=512, K=512)
  gemm_nt<short, false><<<dim3(4, 4, 16), 256, 0, stream>>>(
      M2, CC, 512, wqT, 0, 512, M3, CC, 512, nullptr, 512);

  // out[b][o][l] = sum_c M3[o][c] * xT[b][l][c] + b_out[o]  (fp32)
  gemm_nt<float, true><<<dim3(32, 4, 16), 256, 0, stream>>>(
      M3, CC, 512, xT, CL, 512, out, CL, 4096, b_out, 512);
}